// Round 4
// baseline (459.566 us; speedup 1.0000x reference)
//
#include <hip/hip_runtime.h>

typedef _Float16 f16;
typedef _Float16 f16x4 __attribute__((ext_vector_type(4)));
typedef _Float16 f16x8 __attribute__((ext_vector_type(8)));
typedef float f32x4 __attribute__((ext_vector_type(4)));

constexpr int NN = 50000;
constexpr int NE = 800000;
constexpr int MP = 50048;   // 391 * 128 (padded row count)
constexpr int CAP = 64;     // bucket capacity per node (Poisson(16) tail ~1e-18)

// fp32 x [50000][128] -> f16 xh [MP][128], pad rows zeroed
__global__ void conv_x(const float* __restrict__ x, f16* __restrict__ xh) {
  int i = blockIdx.x * 256 + threadIdx.x;  // 8 elements per thread
  if (i >= MP * 128 / 8) return;
  int row = i >> 4;
  f16x8 o;
  if (row < NN) {
    const float4* p = (const float4*)(x + (size_t)i * 8);
    float4 a = p[0], b = p[1];
    o = f16x8{(f16)a.x, (f16)a.y, (f16)a.z, (f16)a.w,
              (f16)b.x, (f16)b.y, (f16)b.z, (f16)b.w};
  } else {
    o = f16x8{0, 0, 0, 0, 0, 0, 0, 0};
  }
  *(f16x8*)(xh + (size_t)i * 8) = o;
}

// all four weight transposes in one launch: W [K][N] fp32 -> Wt [N][K] f16
__global__ void conv_w_all(const float* __restrict__ W1i, const float* __restrict__ W2i,
                           const float* __restrict__ W1f, const float* __restrict__ W2f,
                           f16* __restrict__ w1it, f16* __restrict__ w2it,
                           f16* __restrict__ w1ft, f16* __restrict__ w2ft) {
  int i = blockIdx.x * 256 + threadIdx.x;  // total 393216
  const float* W; f16* Wt; int K, N, idx;
  if (i < 65536)       { W = W1i; Wt = w1it; K = 128; N = 512; idx = i; }
  else if (i < 196608) { W = W2i; Wt = w2it; K = 512; N = 256; idx = i - 65536; }
  else if (i < 327680) { W = W1f; Wt = w1ft; K = 256; N = 512; idx = i - 196608; }
  else                 { W = W2f; Wt = w2ft; K = 512; N = 128; idx = i - 327680; }
  int n = idx / K, k = idx - n * K;
  Wt[idx] = (f16)W[(size_t)k * N + n];
}

// build per-dst buckets: one int atomic per edge
__global__ void scatter_edges(const int* __restrict__ src, const int* __restrict__ dst,
                              int* __restrict__ cnt, int* __restrict__ bucket) {
  int e = blockIdx.x * 256 + threadIdx.x;
  if (e >= NE) return;
  int d = dst[e];
  int slot = atomicAdd(&cnt[d], 1);
  if (slot < CAP) bucket[(size_t)d * CAP + slot] = src[e];
}

// one wave per node. Half-wave row layout: lane = (half = l>>5, chunk = l&31);
// each lane loads 16B, one wave-gather covers TWO h-rows; 8-deep => 16 edges in flight.
__global__ __launch_bounds__(256) void agg_kernel(const f16* __restrict__ h,
    const int* __restrict__ cnt, const int* __restrict__ bucket,
    f16* __restrict__ hagg) {
  int wid = (blockIdx.x * 256 + threadIdx.x) >> 6;
  int l = threadIdx.x & 63;
  if (wid >= NN) return;
  int deg = cnt[wid];
  if (deg > CAP) deg = CAP;
  int s_all = bucket[(size_t)wid * CAP + l];  // lane l holds slot l
  const int half = l >> 5;
  const int lc = l & 31;
  const f16* hb = h + lc * 8;
  float a[8] = {0.f, 0.f, 0.f, 0.f, 0.f, 0.f, 0.f, 0.f};
  int e = 0;
  for (; e + 16 <= deg; e += 16) {
    f16x8 v[8];
    #pragma unroll
    for (int u = 0; u < 8; ++u) {
      int s = __shfl(s_all, e + 2 * u + half);
      v[u] = *(const f16x8*)(hb + (size_t)s * 256);
    }
    #pragma unroll
    for (int u = 0; u < 8; ++u)
      #pragma unroll
      for (int j = 0; j < 8; ++j)
        a[j] += (float)v[u][j];
  }
  for (; e + 2 <= deg; e += 2) {
    int s = __shfl(s_all, e + half);
    f16x8 v = *(const f16x8*)(hb + (size_t)s * 256);
    #pragma unroll
    for (int j = 0; j < 8; ++j) a[j] += (float)v[j];
  }
  if (e < deg) {  // odd leftover: only half 0 contributes
    int s = __shfl(s_all, e);
    if (half == 0) {
      f16x8 v = *(const f16x8*)(hb + (size_t)s * 256);
      #pragma unroll
      for (int j = 0; j < 8; ++j) a[j] += (float)v[j];
    }
  }
  #pragma unroll
  for (int j = 0; j < 8; ++j) a[j] += __shfl_xor(a[j], 32);
  if (half == 0) {
    f16x8 o;
    #pragma unroll
    for (int j = 0; j < 8; ++j) o[j] = (f16)a[j];
    *(f16x8*)(hagg + (size_t)wid * 256 + lc * 8) = o;
  }
}

// C[M][N] = act(A[M][K] @ Wt[N][K]^T + bias). BM=BN=128, BK=64, 4 waves.
// m97-style: linear LDS + global_load_lds(16B) staging, 2 barriers per K-step.
template<int K, int N, bool RELU, bool OUT_F32>
__global__ __launch_bounds__(256, 2) void gemm_kernel(
    const f16* __restrict__ A, const f16* __restrict__ Wt,
    const float* __restrict__ bias, void* __restrict__ Cout, int Mvalid) {
  __shared__ f16 As[128 * 64];
  __shared__ f16 Bs[128 * 64];
  const int m0 = blockIdx.x * 128;
  const int n0 = blockIdx.y * 128;
  const int t = threadIdx.x;
  const int w = t >> 6, l = t & 63;
  const int wm = (w >> 1) * 64, wn = (w & 1) * 64;
  const int lg = l >> 4, lr = l & 15;
  // staging: instr `it`, thread t covers row rs+it*32, cols cs..cs+7 of the K-tile
  const int rs = t >> 3, cs = (t & 7) * 8;
  const f16* Ag = A + (size_t)(m0 + rs) * K + cs;
  const f16* Bg = Wt + (size_t)(n0 + rs) * K + cs;
  f16* Al = As + (size_t)t * 8;   // + it*2048 elems; byte off = (it*256+t)*16
  f16* Bl = Bs + (size_t)t * 8;
  f32x4 acc[4][4] = {};
  for (int kt = 0; kt < K; kt += 64) {
    #pragma unroll
    for (int it = 0; it < 4; ++it) {
      __builtin_amdgcn_global_load_lds(
          (const __attribute__((address_space(1))) void*)(Ag + (size_t)(it * 32) * K + kt),
          (__attribute__((address_space(3))) void*)(Al + it * 2048), 16, 0, 0);
      __builtin_amdgcn_global_load_lds(
          (const __attribute__((address_space(1))) void*)(Bg + (size_t)(it * 32) * K + kt),
          (__attribute__((address_space(3))) void*)(Bl + it * 2048), 16, 0, 0);
    }
    __syncthreads();  // drains vmcnt before barrier
    #pragma unroll
    for (int kk = 0; kk < 64; kk += 32) {
      f16x8 af[4], bf[4];
      #pragma unroll
      for (int i = 0; i < 4; ++i) {
        // operand element j: k = 16*(j>=4) + 4*(lane>>4) + (j&3)
        const f16* p = &As[(wm + i * 16 + lr) * 64 + kk + lg * 4];
        f16x4 alo = *(const f16x4*)p;
        f16x4 ahi = *(const f16x4*)(p + 16);
        af[i] = __builtin_shufflevector(alo, ahi, 0, 1, 2, 3, 4, 5, 6, 7);
        const f16* q = &Bs[(wn + i * 16 + lr) * 64 + kk + lg * 4];
        f16x4 blo = *(const f16x4*)q;
        f16x4 bhi = *(const f16x4*)(q + 16);
        bf[i] = __builtin_shufflevector(blo, bhi, 0, 1, 2, 3, 4, 5, 6, 7);
      }
      #pragma unroll
      for (int i = 0; i < 4; ++i)
        #pragma unroll
        for (int j = 0; j < 4; ++j)
          acc[i][j] = __builtin_amdgcn_mfma_f32_16x16x32_f16(af[i], bf[j], acc[i][j], 0, 0, 0);
    }
    __syncthreads();
  }
  // epilogue: C/D layout col = lane&15, row = (lane>>4)*4 + reg
  #pragma unroll
  for (int i = 0; i < 4; ++i) {
    #pragma unroll
    for (int j = 0; j < 4; ++j) {
      int n = n0 + wn + j * 16 + lr;
      float bv = bias[n];
      #pragma unroll
      for (int r = 0; r < 4; ++r) {
        int m = m0 + wm + i * 16 + lg * 4 + r;
        float v = acc[i][j][r] + bv;
        if (RELU) v = v > 0.f ? v : 0.f;
        if (OUT_F32) {
          if (m < Mvalid) ((float*)Cout)[(size_t)m * N + n] = v;
        } else {
          ((f16*)Cout)[(size_t)m * N + n] = (f16)v;
        }
      }
    }
  }
}

extern "C" void kernel_launch(void* const* d_in, const int* in_sizes, int n_in,
                              void* d_out, int out_size, void* d_ws, size_t ws_size,
                              hipStream_t stream) {
  const float* x   = (const float*)d_in[0];
  const int*   ei  = (const int*)d_in[1];   // [2][NE]: row0 = src, row1 = dst
  const float* W1i = (const float*)d_in[2];
  const float* b1i = (const float*)d_in[3];
  const float* W2i = (const float*)d_in[4];
  const float* b2i = (const float*)d_in[5];
  const float* W1f = (const float*)d_in[6];
  const float* b1f = (const float*)d_in[7];
  const float* W2f = (const float*)d_in[8];
  const float* b2f = (const float*)d_in[9];
  float* out = (float*)d_out;

  char* ws = (char*)d_ws;
  size_t off = 0;
  auto alloc = [&](size_t bytes) -> void* {
    void* p = ws + off;
    off += (bytes + 255) & ~(size_t)255;
    return p;
  };
  f16* xh    = (f16*)alloc((size_t)MP * 128 * 2);
  f16* w1it  = (f16*)alloc((size_t)512 * 128 * 2);
  f16* w2it  = (f16*)alloc((size_t)256 * 512 * 2);
  f16* w1ft  = (f16*)alloc((size_t)512 * 256 * 2);
  f16* w2ft  = (f16*)alloc((size_t)128 * 512 * 2);
  f16* hid   = (f16*)alloc((size_t)MP * 512 * 2);  // reused for hidden1 and hidden2
  f16* h     = (f16*)alloc((size_t)MP * 256 * 2);
  f16* hagg  = (f16*)alloc((size_t)MP * 256 * 2);
  int* cnt   = (int*)alloc((size_t)NN * 4);
  int* bucket= (int*)alloc((size_t)NN * CAP * 4);

  hipMemsetAsync(cnt, 0, (size_t)NN * 4, stream);
  conv_x<<<(MP * 128 / 8 + 255) / 256, 256, 0, stream>>>(x, xh);
  conv_w_all<<<393216 / 256, 256, 0, stream>>>(W1i, W2i, W1f, W2f, w1it, w2it, w1ft, w2ft);
  scatter_edges<<<(NE + 255) / 256, 256, 0, stream>>>(ei, ei + NE, cnt, bucket);

  gemm_kernel<128, 512, true,  false><<<dim3(MP / 128, 4), 256, 0, stream>>>(xh,   w1it, b1i, hid, MP);
  gemm_kernel<512, 256, false, false><<<dim3(MP / 128, 2), 256, 0, stream>>>(hid,  w2it, b2i, h,   MP);
  agg_kernel<<<(NN * 64) / 256, 256, 0, stream>>>(h, cnt, bucket, hagg);
  gemm_kernel<256, 512, true,  false><<<dim3(MP / 128, 4), 256, 0, stream>>>(hagg, w1ft, b1f, hid, MP);
  gemm_kernel<512, 128, false, true ><<<dim3(MP / 128, 1), 256, 0, stream>>>(hid,  w2ft, b2f, out, NN);
}

// Round 5
// 205.615 us; speedup vs baseline: 2.2351x; 2.2351x over previous
//
#include <hip/hip_runtime.h>

typedef _Float16 f16;
typedef _Float16 f16x4 __attribute__((ext_vector_type(4)));
typedef _Float16 f16x8 __attribute__((ext_vector_type(8)));
typedef float f32x4 __attribute__((ext_vector_type(4)));

constexpr int NN = 50000;
constexpr int NE = 800000;
constexpr int MP = 50048;   // 782 * 64 (padded row count)
constexpr int CAP = 64;     // bucket capacity per node (Poisson(16) tail ~1e-18)

// fp32 x [50000][128] -> f16 xh [MP][128], pad rows zeroed
__global__ void conv_x(const float* __restrict__ x, f16* __restrict__ xh) {
  int i = blockIdx.x * 256 + threadIdx.x;  // 8 elements per thread
  if (i >= MP * 128 / 8) return;
  int row = i >> 4;
  f16x8 o;
  if (row < NN) {
    const float4* p = (const float4*)(x + (size_t)i * 8);
    float4 a = p[0], b = p[1];
    o = f16x8{(f16)a.x, (f16)a.y, (f16)a.z, (f16)a.w,
              (f16)b.x, (f16)b.y, (f16)b.z, (f16)b.w};
  } else {
    o = f16x8{0, 0, 0, 0, 0, 0, 0, 0};
  }
  *(f16x8*)(xh + (size_t)i * 8) = o;
}

// all four weight transposes in one launch: W [K][N] fp32 -> Wt [N][K] f16
__global__ void conv_w_all(const float* __restrict__ W1i, const float* __restrict__ W2i,
                           const float* __restrict__ W1f, const float* __restrict__ W2f,
                           f16* __restrict__ w1it, f16* __restrict__ w2it,
                           f16* __restrict__ w1ft, f16* __restrict__ w2ft) {
  int i = blockIdx.x * 256 + threadIdx.x;  // total 393216
  const float* W; f16* Wt; int K, N, idx;
  if (i < 65536)       { W = W1i; Wt = w1it; K = 128; N = 512; idx = i; }
  else if (i < 196608) { W = W2i; Wt = w2it; K = 512; N = 256; idx = i - 65536; }
  else if (i < 327680) { W = W1f; Wt = w1ft; K = 256; N = 512; idx = i - 196608; }
  else                 { W = W2f; Wt = w2ft; K = 512; N = 128; idx = i - 327680; }
  int n = idx / K, k = idx - n * K;
  Wt[idx] = (f16)W[(size_t)k * N + n];
}

// build per-dst buckets: one int atomic per edge
__global__ void scatter_edges(const int* __restrict__ src, const int* __restrict__ dst,
                              int* __restrict__ cnt, int* __restrict__ bucket) {
  int e = blockIdx.x * 256 + threadIdx.x;
  if (e >= NE) return;
  int d = dst[e];
  int slot = atomicAdd(&cnt[d], 1);
  if (slot < CAP) bucket[(size_t)d * CAP + slot] = src[e];
}

// one wave per node. Half-wave row layout: lane = (half = l>>5, chunk = l&31);
// each lane loads 16B, one wave-gather covers TWO h-rows; 8-deep => 16 edges in flight.
__global__ __launch_bounds__(256) void agg_kernel(const f16* __restrict__ h,
    const int* __restrict__ cnt, const int* __restrict__ bucket,
    f16* __restrict__ hagg) {
  int wid = (blockIdx.x * 256 + threadIdx.x) >> 6;
  int l = threadIdx.x & 63;
  if (wid >= NN) return;
  int deg = cnt[wid];
  if (deg > CAP) deg = CAP;
  int s_all = bucket[(size_t)wid * CAP + l];  // lane l holds slot l
  const int half = l >> 5;
  const int lc = l & 31;
  const f16* hb = h + lc * 8;
  float a[8] = {0.f, 0.f, 0.f, 0.f, 0.f, 0.f, 0.f, 0.f};
  int e = 0;
  for (; e + 16 <= deg; e += 16) {
    f16x8 v[8];
    #pragma unroll
    for (int u = 0; u < 8; ++u) {
      int s = __shfl(s_all, e + 2 * u + half);
      v[u] = *(const f16x8*)(hb + (size_t)s * 256);
    }
    #pragma unroll
    for (int u = 0; u < 8; ++u)
      #pragma unroll
      for (int j = 0; j < 8; ++j)
        a[j] += (float)v[u][j];
  }
  for (; e + 2 <= deg; e += 2) {
    int s = __shfl(s_all, e + half);
    f16x8 v = *(const f16x8*)(hb + (size_t)s * 256);
    #pragma unroll
    for (int j = 0; j < 8; ++j) a[j] += (float)v[j];
  }
  if (e < deg) {  // odd leftover: only half 0 contributes
    int s = __shfl(s_all, e);
    if (half == 0) {
      f16x8 v = *(const f16x8*)(hb + (size_t)s * 256);
      #pragma unroll
      for (int j = 0; j < 8; ++j) a[j] += (float)v[j];
    }
  }
  #pragma unroll
  for (int j = 0; j < 8; ++j) a[j] += __shfl_xor(a[j], 32);
  if (half == 0) {
    f16x8 o;
    #pragma unroll
    for (int j = 0; j < 8; ++j) o[j] = (f16)a[j];
    *(f16x8*)(hagg + (size_t)wid * 256 + lc * 8) = o;
  }
}

// C[M][N] = act(A[M][K] @ Wt[N][K]^T + bias). BMx128 tile, BK=64, 4 waves.
// global_load_lds staging (linear LDS dest) + XOR-swizzled global SOURCE;
// fragment reads = single ds_read_b128 with matching XOR (k-permutation freedom:
// any slot->k bijection works if A and B share it).
template<int K, int N, int BM, bool RELU, bool OUT_F32>
__global__ __launch_bounds__(256, 2) void gemm_kernel(
    const f16* __restrict__ A, const f16* __restrict__ Wt,
    const float* __restrict__ bias, void* __restrict__ Cout, int Mvalid) {
  constexpr int WM = BM / 2;    // wave tile rows (64 or 32)
  constexpr int MI = WM / 16;   // A fragments per wave (4 or 2)
  constexpr int AIT = BM / 32;  // A staging instructions (4 or 2)
  __shared__ f16 As[BM * 64];
  __shared__ f16 Bs[128 * 64];
  const int m0 = blockIdx.x * BM;
  const int n0 = blockIdx.y * 128;
  const int t = threadIdx.x;
  const int w = t >> 6, l = t & 63;
  const int wm = (w >> 1) * WM, wn = (w & 1) * 64;
  const int lg = l >> 4, lr = l & 15;
  // staging: per instr, 32 rows x 8 chunks of 16B; physical chunk pc holds
  // logical chunk pc ^ (row & 7)
  const int rs = t >> 3, pc = t & 7;
  f32x4 acc[MI][4] = {};
  for (int kt = 0; kt < K; kt += 64) {
    #pragma unroll
    for (int it = 0; it < AIT; ++it) {
      int r = it * 32 + rs;
      int lc = pc ^ (r & 7);
      __builtin_amdgcn_global_load_lds(
          (const __attribute__((address_space(1))) void*)(A + (size_t)(m0 + r) * K + kt + lc * 8),
          (__attribute__((address_space(3))) void*)(As + (it * 256 + t) * 8), 16, 0, 0);
    }
    #pragma unroll
    for (int it = 0; it < 4; ++it) {
      int r = it * 32 + rs;
      int lc = pc ^ (r & 7);
      __builtin_amdgcn_global_load_lds(
          (const __attribute__((address_space(1))) void*)(Wt + (size_t)(n0 + r) * K + kt + lc * 8),
          (__attribute__((address_space(3))) void*)(Bs + (it * 256 + t) * 8), 16, 0, 0);
    }
    __syncthreads();  // drains vmcnt before barrier
    #pragma unroll
    for (int kk = 0; kk < 64; kk += 32) {
      const int c = (kk >> 3) + lg;  // logical chunk: slot j of group lg <-> k = kk + lg*8 + j
      f16x8 af[MI], bf[4];
      #pragma unroll
      for (int i = 0; i < MI; ++i) {
        int ra = wm + i * 16 + lr;
        af[i] = *(const f16x8*)&As[ra * 64 + ((c ^ (ra & 7)) << 3)];
      }
      #pragma unroll
      for (int j = 0; j < 4; ++j) {
        int rb = wn + j * 16 + lr;
        bf[j] = *(const f16x8*)&Bs[rb * 64 + ((c ^ (rb & 7)) << 3)];
      }
      #pragma unroll
      for (int i = 0; i < MI; ++i)
        #pragma unroll
        for (int j = 0; j < 4; ++j)
          acc[i][j] = __builtin_amdgcn_mfma_f32_16x16x32_f16(af[i], bf[j], acc[i][j], 0, 0, 0);
    }
    __syncthreads();
  }
  // epilogue: C/D layout col = lane&15, row = (lane>>4)*4 + reg
  #pragma unroll
  for (int i = 0; i < MI; ++i) {
    #pragma unroll
    for (int j = 0; j < 4; ++j) {
      int n = n0 + wn + j * 16 + lr;
      float bv = bias[n];
      #pragma unroll
      for (int r = 0; r < 4; ++r) {
        int m = m0 + wm + i * 16 + lg * 4 + r;
        float v = acc[i][j][r] + bv;
        if (RELU) v = v > 0.f ? v : 0.f;
        if (OUT_F32) {
          if (m < Mvalid) ((float*)Cout)[(size_t)m * N + n] = v;
        } else {
          ((f16*)Cout)[(size_t)m * N + n] = (f16)v;
        }
      }
    }
  }
}

extern "C" void kernel_launch(void* const* d_in, const int* in_sizes, int n_in,
                              void* d_out, int out_size, void* d_ws, size_t ws_size,
                              hipStream_t stream) {
  const float* x   = (const float*)d_in[0];
  const int*   ei  = (const int*)d_in[1];   // [2][NE]: row0 = src, row1 = dst
  const float* W1i = (const float*)d_in[2];
  const float* b1i = (const float*)d_in[3];
  const float* W2i = (const float*)d_in[4];
  const float* b2i = (const float*)d_in[5];
  const float* W1f = (const float*)d_in[6];
  const float* b1f = (const float*)d_in[7];
  const float* W2f = (const float*)d_in[8];
  const float* b2f = (const float*)d_in[9];
  float* out = (float*)d_out;

  char* ws = (char*)d_ws;
  size_t off = 0;
  auto alloc = [&](size_t bytes) -> void* {
    void* p = ws + off;
    off += (bytes + 255) & ~(size_t)255;
    return p;
  };
  f16* xh    = (f16*)alloc((size_t)MP * 128 * 2);
  f16* w1it  = (f16*)alloc((size_t)512 * 128 * 2);
  f16* w2it  = (f16*)alloc((size_t)256 * 512 * 2);
  f16* w1ft  = (f16*)alloc((size_t)512 * 256 * 2);
  f16* w2ft  = (f16*)alloc((size_t)128 * 512 * 2);
  f16* hid   = (f16*)alloc((size_t)MP * 512 * 2);  // reused for hidden1 and hidden2
  f16* h     = (f16*)alloc((size_t)MP * 256 * 2);
  f16* hagg  = (f16*)alloc((size_t)MP * 256 * 2);
  int* cnt   = (int*)alloc((size_t)NN * 4);
  int* bucket= (int*)alloc((size_t)NN * CAP * 4);

  hipMemsetAsync(cnt, 0, (size_t)NN * 4, stream);
  conv_x<<<(MP * 128 / 8 + 255) / 256, 256, 0, stream>>>(x, xh);
  conv_w_all<<<393216 / 256, 256, 0, stream>>>(W1i, W2i, W1f, W2f, w1it, w2it, w1ft, w2ft);
  scatter_edges<<<(NE + 255) / 256, 256, 0, stream>>>(ei, ei + NE, cnt, bucket);

  gemm_kernel<128, 512, 128, true,  false><<<dim3(MP / 128, 4), 256, 0, stream>>>(xh,   w1it, b1i, hid, MP);
  gemm_kernel<512, 256, 128, false, false><<<dim3(MP / 128, 2), 256, 0, stream>>>(hid,  w2it, b2i, h,   MP);
  agg_kernel<<<(NN * 64) / 256, 256, 0, stream>>>(h, cnt, bucket, hagg);
  gemm_kernel<256, 512, 128, true,  false><<<dim3(MP / 128, 4), 256, 0, stream>>>(hagg, w1ft, b1f, hid, MP);
  gemm_kernel<512, 128, 64,  false, true ><<<dim3(MP / 64, 1),  256, 0, stream>>>(hid,  w2ft, b2f, out, NN);
}